// Round 16
// baseline (78.790 us; speedup 1.0000x reference)
//
#include <hip/hip_runtime.h>
#include <hip/hip_bf16.h>
#include <math.h>

#define DEVI __device__ __forceinline__

typedef __attribute__((ext_vector_type(4))) float f32x4;
typedef __attribute__((ext_vector_type(8))) short bf16x8;

DEVI unsigned short f2bf(float f) {
  union { float f; unsigned int u; } v; v.f = f;
  return (unsigned short)((v.u + 0x7FFFu + ((v.u >> 16) & 1u)) >> 16);
}
DEVI float bf2f(unsigned short s) {
  union { unsigned int u; float f; } v; v.u = ((unsigned int)s) << 16; return v.f;
}
DEVI bf16x8 pack8(f32x4 a, f32x4 b) {
  bf16x8 r;
  r[0] = (short)f2bf(a[0]); r[1] = (short)f2bf(a[1]);
  r[2] = (short)f2bf(a[2]); r[3] = (short)f2bf(a[3]);
  r[4] = (short)f2bf(b[0]); r[5] = (short)f2bf(b[1]);
  r[6] = (short)f2bf(b[2]); r[7] = (short)f2bf(b[3]);
  return r;
}
DEVI void gload16(const unsigned short* g, unsigned short* l) {
  __builtin_amdgcn_global_load_lds(
      (const __attribute__((address_space(1))) unsigned int*)g,
      (__attribute__((address_space(3))) unsigned int*)l, 16, 0, 0);
}
// raw workgroup barrier WITHOUT the implicit vmcnt(0) drain of __syncthreads
#define SBAR() do { asm volatile("" ::: "memory"); \
                    __builtin_amdgcn_s_barrier();  \
                    asm volatile("" ::: "memory"); } while (0)

// ==== prep: weights f32[K][512] -> bf16 [512][K] swz ; f32[M][K] -> bf16 [M][K] swz
// swizzle: within each 64-elem k-group, kblock kb of row n stored at ((kb+n)&7).
struct PrepJobs {
  const float* src[9];
  unsigned short* dst[9];
  int K[9];
  int base[9];
  int type[9];   // 0 = weight transpose (64x64 tiles), 1 = row-major convert
};

__global__ __launch_bounds__(256) void prep(PrepJobs J) {
  __shared__ float t[64][65];   // 16.6 KB
  int tile = blockIdx.x;
  int job = 0;
  while (job < 8 && tile >= J.base[job + 1]) ++job;
  int tl = tile - J.base[job];
  int K = J.K[job];
  if (J.type[job] == 0) {
    int tn = tl & 7, tk = tl >> 3;   // 512/64 = 8 n-tiles
    int x = threadIdx.x & 63, y = threadIdx.x >> 6;
    const float* s = J.src[job];
    int k0 = tk * 64, n0 = tn * 64;
#pragma unroll
    for (int yy = y; yy < 64; yy += 4)
      t[yy][x] = s[(size_t)(k0 + yy) * 512 + n0 + x];
    __syncthreads();
    unsigned short* d = J.dst[job];
    int kb = (x >> 3) & 7, ko = x & 7;   // k = k0 + x, k0 % 64 == 0
#pragma unroll
    for (int yy = y; yy < 64; yy += 4) {
      int n = n0 + yy;
      int kswz = k0 + (((kb + n) & 7) << 3) + ko;
      d[(size_t)n * K + kswz] = f2bf(t[x][yy]);
    }
  } else {
    int nk = K >> 6;
    int rt = tl / nk;
    int r0 = rt * 64, k0 = (tl - rt * nk) * 64;
    int r = threadIdx.x >> 2, kq = threadIdx.x & 3;
    int row = r0 + r;
    const float* s = J.src[job] + (size_t)row * K + k0 + kq * 16;
    f32x4 a0 = *(const f32x4*)s;
    f32x4 a1 = *(const f32x4*)(s + 4);
    f32x4 a2 = *(const f32x4*)(s + 8);
    f32x4 a3 = *(const f32x4*)(s + 12);
    unsigned short* d = J.dst[job] + (size_t)row * K + k0;
    int kb0 = kq * 2;
    *(bf16x8*)(d + ((kb0 + row) & 7) * 8) = pack8(a0, a1);
    *(bf16x8*)(d + ((kb0 + 1 + row) & 7) * 8) = pack8(a2, a3);
  }
}

// ==== proj GEMM (2,4)=64x128: A direct-to-REGISTERS, B via LDS DMA =========
// 4 waves (2m x 2n), wave tile 32x64. A-fragments are per-lane constant
// addresses (swizzle folds into base) -> global bf16x8 loads into a
// double-buffered register set, prefetched one full K-step ahead. B is
// global_load_lds double-buffered. LDS = 32 KB -> 4 blocks/CU.
// Steady state: after compute(t) issue {A(t+2) regs, B(t+2) DMA}; top-of-step
// vmcnt(8) retires exactly {A(t),B(t)}. K-loop unrolled x2 (nt always even)
// so register-set indices are compile-time (rule #20).
struct PJob {
  const unsigned short* A0;
  const unsigned short* Bt;
  const float* bias;        // may be nullptr
  unsigned short* Cb;
  int Astride, Bstride, Cstride, nTilesN, nt, mode, tileBase;
};
struct PBatch { PJob j[7]; int njobs; };

__global__ __launch_bounds__(256, 4) void gemm_areg(PBatch batch) {
  int gt = blockIdx.x;
  int job = 0;
#pragma unroll
  for (int i = 1; i < 7; ++i)
    if (i < batch.njobs && gt >= batch.j[i].tileBase) job = i;
  PJob J = batch.j[job];
  int tl = gt - J.tileBase;
  int bm = (tl / J.nTilesN) * 64, bn = (tl % J.nTilesN) * 128;

  __shared__ __align__(16) unsigned short Lb[2][128 * 64];   // 32 KB

  int tid = threadIdx.x;
  int wave = tid >> 6, lane = tid & 63;
  int lrow = lane & 15, lq = lane >> 4;
  int wr = (wave >> 1) * 32, wc = (wave & 1) * 64;
  f32x4 acc[2][4] = {};

  int nt = J.nt;

  // per-lane constant A addresses (swizzle folded: row fixed per (mi))
  const unsigned short* aptr[2][2];   // [mi][kc]
#pragma unroll
  for (int mi = 0; mi < 2; ++mi) {
    int rowg = bm + wr + mi * 16 + lrow;
#pragma unroll
    for (int kc = 0; kc < 2; ++kc) {
      int kb = kc * 4 + lq;
      aptr[mi][kc] = J.A0 + (size_t)rowg * J.Astride + ((kb + rowg) & 7) * 8;
    }
  }

  bf16x8 RA0[2][2], RA1[2][2];   // two A-tile register sets [mi][kc]

  auto aload = [&](int t, bf16x8 (&RA)[2][2]) {
#pragma unroll
    for (int mi = 0; mi < 2; ++mi)
#pragma unroll
      for (int kc = 0; kc < 2; ++kc)
        RA[mi][kc] = *(const bf16x8*)(aptr[mi][kc] + (t << 6));
  };
  auto bdma = [&](int t, int buf) {
    const unsigned short* GB = J.Bt + (size_t)bn * J.Bstride + (size_t)(t << 6);
#pragma unroll
    for (int p = 0; p < 4; ++p) {
      int s = p * 256 + tid;
      gload16(GB + (size_t)(s >> 3) * J.Bstride + (s & 7) * 8,
              &Lb[buf][(size_t)(p * 256 + wave * 64) * 8]);
    }
  };
  auto compute = [&](int buf, const bf16x8 (&RA)[2][2]) {
    __builtin_amdgcn_s_setprio(1);
#pragma unroll
    for (int kc = 0; kc < 2; ++kc) {
      int kb = kc * 4 + lq;
      bf16x8 bv[4];
#pragma unroll
      for (int ni = 0; ni < 4; ++ni) {
        int r = wc + ni * 16 + lrow;
        bv[ni] = *(const bf16x8*)&Lb[buf][r * 64 + ((kb + r) & 7) * 8];
      }
#pragma unroll
      for (int mi = 0; mi < 2; ++mi)
#pragma unroll
        for (int ni = 0; ni < 4; ++ni)
          acc[mi][ni] = __builtin_amdgcn_mfma_f32_16x16x32_bf16(RA[mi][kc], bv[ni], acc[mi][ni], 0, 0, 0);
    }
    __builtin_amdgcn_s_setprio(0);
  };

  // prologue: issue A(0),B(0),A(1),B(1)  -> 16 outstanding
  aload(0, RA0); bdma(0, 0);
  aload(1, RA1); bdma(1, 1);

  for (int t = 0; t < nt; t += 2) {     // nt is even (8 or 32)
    // -- even sub-iter: tile t, buf 0, regs RA0 --
    asm volatile("s_waitcnt vmcnt(8)" ::: "memory");   // A(t),B(t) landed
    SBAR();
    compute(0, RA0);
    SBAR();
    if (t + 2 < nt) { aload(t + 2, RA0); bdma(t + 2, 0); }
    // -- odd sub-iter: tile t+1, buf 1, regs RA1 --
    if (t + 2 < nt) asm volatile("s_waitcnt vmcnt(8)" ::: "memory");
    else            asm volatile("s_waitcnt vmcnt(0)" ::: "memory");
    SBAR();
    compute(1, RA1);
    SBAR();
    if (t + 3 < nt) { aload(t + 3, RA1); bdma(t + 3, 1); }
  }

  // epilogue: C/D layout col=lane&15, row=lq*4+reg
#pragma unroll
  for (int mi = 0; mi < 2; ++mi) {
#pragma unroll
    for (int ni = 0; ni < 4; ++ni) {
      int gn = bn + wc + ni * 16 + lrow;
      float bvs = J.bias ? J.bias[gn] : 0.f;
      int gm0 = bm + wr + mi * 16 + lq * 4;
      if (J.mode == 0) {
#pragma unroll
        for (int r = 0; r < 4; ++r)
          J.Cb[(size_t)(gm0 + r) * J.Cstride + gn] = f2bf(acc[mi][ni][r] + bvs);
      } else {
        // mode 2: store so row-major [M][N] reads as a swizzled GEMM operand
#pragma unroll
        for (int r = 0; r < 4; ++r) {
          int row = gm0 + r;
          int col = (gn & ~63) | (((((gn >> 3) & 7) + row) & 7) << 3) | (gn & 7);
          J.Cb[(size_t)row * J.Cstride + col] = f2bf(acc[mi][ni][r] + bvs);
        }
      }
    }
  }
}

// ==== stage3: hybrid svgemm (blocks < nGemm) + scores/softmax (rest) ========
// Single 32 KB LDS union -> 5 blocks/CU for both halves.
struct HJob {
  const unsigned short* A0;
  const unsigned short* Bt;
  unsigned short* Cb;
  int Astride, Bstride, Cstride, nTilesN, nt, tileBase;
};
struct S3Args {
  HJob g[2];
  int nGemm;                 // gemm blocks count (288)
  const unsigned short* qh;
  const unsigned short* s_key;
  const unsigned short* t_key;
  float* Wsw;
  float* Wtw;
};

__global__ __launch_bounds__(256) void stage3(S3Args A) {
  __shared__ __align__(16) unsigned short SH[2][8192];   // 32 KB union
  int tid = threadIdx.x;
  int wave = tid >> 6, lane = tid & 63;
  int lrow = lane & 15, lq = lane >> 4;

  if ((int)blockIdx.x < A.nGemm) {
    // ---- (2,2) 64x64 GEMM, pure-DMA double buffer, counted vmcnt ----
    int gt = blockIdx.x;
    HJob J = (gt >= A.g[1].tileBase) ? A.g[1] : A.g[0];
    int tl = gt - J.tileBase;
    int bm = (tl / J.nTilesN) * 64, bn = (tl % J.nTilesN) * 64;
    int wr = (wave >> 1) * 32, wc = (wave & 1) * 32;
    f32x4 acc[2][2] = {};
    int nt = J.nt;

    auto stage2 = [&](int t, int buf) {
      const unsigned short* GA = J.A0 + (size_t)bm * J.Astride + (size_t)(t << 6);
      const unsigned short* GB = J.Bt + (size_t)bn * J.Bstride + (size_t)(t << 6);
#pragma unroll
      for (int p = 0; p < 2; ++p) {
        int s = p * 256 + tid;
        gload16(GA + (size_t)(s >> 3) * J.Astride + (s & 7) * 8,
                &SH[buf][(size_t)(p * 256 + wave * 64) * 8]);
      }
#pragma unroll
      for (int p = 0; p < 2; ++p) {
        int s = p * 256 + tid;
        gload16(GB + (size_t)(s >> 3) * J.Bstride + (s & 7) * 8,
                &SH[buf][4096 + (size_t)(p * 256 + wave * 64) * 8]);
      }
    };

    stage2(0, 0);
    if (nt > 1) stage2(1, 1);

    for (int t = 0; t < nt; ++t) {
      if (t + 1 < nt) asm volatile("s_waitcnt vmcnt(4)" ::: "memory");
      else            asm volatile("s_waitcnt vmcnt(0)" ::: "memory");
      SBAR();
      int cur = t & 1;
      __builtin_amdgcn_s_setprio(1);
#pragma unroll
      for (int kc = 0; kc < 2; ++kc) {
        int kb = kc * 4 + lq;
        bf16x8 af[2], bv[2];
#pragma unroll
        for (int mi = 0; mi < 2; ++mi) {
          int r = wr + mi * 16 + lrow;
          af[mi] = *(const bf16x8*)&SH[cur][r * 64 + ((kb + r) & 7) * 8];
        }
#pragma unroll
        for (int ni = 0; ni < 2; ++ni) {
          int r = wc + ni * 16 + lrow;
          bv[ni] = *(const bf16x8*)&SH[cur][4096 + r * 64 + ((kb + r) & 7) * 8];
        }
#pragma unroll
        for (int mi = 0; mi < 2; ++mi)
#pragma unroll
          for (int ni = 0; ni < 2; ++ni)
            acc[mi][ni] = __builtin_amdgcn_mfma_f32_16x16x32_bf16(af[mi], bv[ni], acc[mi][ni], 0, 0, 0);
      }
      __builtin_amdgcn_s_setprio(0);
      SBAR();
      if (t + 2 < nt) stage2(t + 2, cur);
    }
#pragma unroll
    for (int mi = 0; mi < 2; ++mi) {
#pragma unroll
      for (int ni = 0; ni < 2; ++ni) {
        int gn = bn + wc + ni * 16 + lrow;
        int gm0 = bm + wr + mi * 16 + lq * 4;
#pragma unroll
        for (int r = 0; r < 4; ++r)
          J.Cb[(size_t)(gm0 + r) * J.Cstride + gn] = f2bf(acc[mi][ni][r]);
      }
    }
  } else {
    // ---- scores + separable softmax -> Wsw/Wtw (f32 global) ----
    float (*red)[3][64][4] = (float(*)[3][64][4])&SH[0][0];   // 12 KB of union
    int bid2 = blockIdx.x - A.nGemm;
    int b = bid2 >> 3, lc = bid2 & 7;
    int mat = wave >> 1, kh = wave & 1;
    int row0 = b * 128 + lc * 16;
    const unsigned short* qp = A.qh + (size_t)row0 * 512;
    const unsigned short* key = (mat ? A.s_key : A.t_key) + (size_t)b * 36 * 512;
    f32x4 acc[3] = {};
    for (int kc = kh * 8; kc < kh * 8 + 8; ++kc) {
      int k = kc * 32 + lq * 8;
      bf16x8 af = *(const bf16x8*)(qp + (size_t)lrow * 512 + k);
#pragma unroll
      for (int nf = 0; nf < 3; ++nf) {
        int n = nf * 16 + lrow; if (n > 35) n = 35;   // clamp; masked below
        bf16x8 bv = *(const bf16x8*)(key + (size_t)n * 512 + k);
        acc[nf] = __builtin_amdgcn_mfma_f32_16x16x32_bf16(af, bv, acc[nf], 0, 0, 0);
      }
    }
#pragma unroll
    for (int nf = 0; nf < 3; ++nf)
      *(f32x4*)&red[wave][nf][lane][0] = acc[nf];
    __syncthreads();

    if (kh == 0) {     // waves 0 (mat0 -> Wsw) and 2 (mat1 -> Wtw)
      const float ccs = 0.022097086912079608f;   // 0.5 / sqrt(512)
      float ex[3][4];
#pragma unroll
      for (int r = 0; r < 4; ++r) {
        float a0 = (red[wave][0][lane][r] + red[wave + 1][0][lane][r]) * ccs;
        float a1 = (red[wave][1][lane][r] + red[wave + 1][1][lane][r]) * ccs;
        float a2 = (lrow < 4)
            ? (red[wave][2][lane][r] + red[wave + 1][2][lane][r]) * ccs : -1e30f;
        float mx = fmaxf(fmaxf(a0, a1), a2);
        for (int s = 1; s < 16; s <<= 1) mx = fmaxf(mx, __shfl_xor(mx, s));
        float e0 = __expf(a0 - mx), e1 = __expf(a1 - mx);
        float e2 = (lrow < 4) ? __expf(a2 - mx) : 0.f;
        float sum = e0 + e1 + e2;
        for (int s = 1; s < 16; s <<= 1) sum += __shfl_xor(sum, s);
        float inv = 1.f / sum;
        ex[0][r] = e0 * inv; ex[1][r] = e1 * inv; ex[2][r] = e2 * inv;
      }
      float* W = mat ? A.Wtw : A.Wsw;
#pragma unroll
      for (int nf = 0; nf < 3; ++nf) {
        int col = nf * 16 + lrow;
        if (col < 36) {
#pragma unroll
          for (int r = 0; r < 4; ++r)
            W[(size_t)(row0 + lq * 4 + r) * 36 + col] = ex[nf][r];
        }
      }
    }
  }
}

// ==== wsum: out = relu(Pb + ws@svp + wt@tvp), 16 rows x 256 cols per block ==
__global__ __launch_bounds__(256) void wsum(
    const float* __restrict__ Wsw, const float* __restrict__ Wtw,
    const unsigned short* __restrict__ svp, const unsigned short* __restrict__ tvp,
    const unsigned short* __restrict__ Pb, float* __restrict__ out) {
  __shared__ float wlT[2][36][16];   // 4.6 KB
  int b = blockIdx.x, lc = blockIdx.y;
  int h0 = blockIdx.z << 8;          // 0 or 256
  int tid = threadIdx.x;
  int row0 = b * 128 + lc * 16;
  for (int i = tid; i < 2 * 16 * 36; i += 256) {
    int m = i / 576, rem = i - m * 576;
    int l = rem / 36, j = rem - l * 36;
    wlT[m][j][l] = (m ? Wtw : Wsw)[(size_t)(row0 + l) * 36 + j];
  }
  __syncthreads();

  int lgrp = tid >> 5;               // 0..7, 2 rows each
  int hgrp = tid & 31;               // 0..31, 8 cols each
  float a2[2][8] = {};
#pragma unroll
  for (int m = 0; m < 2; ++m) {
    const unsigned short* V = (m ? tvp : svp) + (size_t)b * 36 * 512 + h0;
    for (int j = 0; j < 36; ++j) {
      float w0 = wlT[m][j][lgrp * 2];
      float w1 = wlT[m][j][lgrp * 2 + 1];
      bf16x8 v = *(const bf16x8*)(V + (size_t)j * 512 + hgrp * 8);
      float vf[8];
#pragma unroll
      for (int hi = 0; hi < 8; ++hi) vf[hi] = bf2f((unsigned short)v[hi]);
#pragma unroll
      for (int hi = 0; hi < 8; ++hi) {
        a2[0][hi] += w0 * vf[hi];
        a2[1][hi] += w1 * vf[hi];
      }
    }
  }
#pragma unroll
  for (int li = 0; li < 2; ++li) {
    int R = row0 + lgrp * 2 + li;
    bf16x8 p = *(const bf16x8*)(Pb + (size_t)R * 512 + h0 + hgrp * 8);
    float* op = out + (size_t)R * 512 + h0 + hgrp * 8;
    f32x4 o0, o1;
#pragma unroll
    for (int hi = 0; hi < 4; ++hi) {
      o0[hi] = fmaxf(bf2f((unsigned short)p[hi]) + a2[li][hi], 0.f);
      o1[hi] = fmaxf(bf2f((unsigned short)p[4 + hi]) + a2[li][4 + hi], 0.f);
    }
    *(f32x4*)op = o0;
    *(f32x4*)(op + 4) = o1;
  }
}

// ---------------------------------------------------------------------------
extern "C" void kernel_launch(void* const* d_in, const int* in_sizes, int n_in,
                              void* d_out, int out_size, void* d_ws, size_t ws_size,
                              hipStream_t stream) {
  (void)in_sizes; (void)n_in; (void)out_size; (void)ws_size;
  const float* query = (const float*)d_in[0];
  const float* src   = (const float*)d_in[1];
  const float* trg   = (const float*)d_in[2];
  const float* Wq  = (const float*)d_in[3];  const float* bq  = (const float*)d_in[4];
  const float* Wsk = (const float*)d_in[5];  const float* bs  = (const float*)d_in[6];
  const float* Wtk = (const float*)d_in[7];  const float* bt  = (const float*)d_in[8];
  const float* Wsv = (const float*)d_in[9];  const float* bsv = (const float*)d_in[10];
  const float* Wtv = (const float*)d_in[11]; const float* btv = (const float*)d_in[12];
  const float* Wo  = (const float*)d_in[13]; const float* bo  = (const float*)d_in[14];

  // workspace (bf16 shorts unless noted) ~38 MB
  unsigned short* WqT    = (unsigned short*)d_ws;     // 512*512
  unsigned short* WsT    = WqT  + 512 * 512;          // 512*2048
  unsigned short* WtT    = WsT  + 512 * 2048;
  unsigned short* WsvT   = WtT  + 512 * 2048;
  unsigned short* WtvT   = WsvT + 512 * 2048;
  unsigned short* WoT    = WtvT + 512 * 2048;         // 512*1536
  unsigned short* queryB = WoT  + 512 * 1536;         // 4096*512 swz
  unsigned short* srcB   = queryB + 4096 * 512;       // 1152*2048 swz
  unsigned short* trgB   = srcB + 1152 * 2048;
  unsigned short* qh     = trgB + 1152 * 2048;        // 4096*512 plain
  unsigned short* s_key  = qh + 4096 * 512;           // 1152*512 plain
  unsigned short* t_key  = s_key + 1152 * 512;
  unsigned short* s_val  = t_key + 1152 * 512;        // 1152*512 A-swz (mode 2)
  unsigned short* t_val  = s_val + 1152 * 512;
  unsigned short* svp    = t_val + 1152 * 512;        // 1152*512 plain
  unsigned short* tvp    = svp + 1152 * 512;
  unsigned short* Pb     = tvp + 1152 * 512;          // 4096*512 plain
  float* Wsw = (float*)(Pb + 4096 * 512);             // 4096*36 f32
  float* Wtw = Wsw + 4096 * 36;
  float* out = (float*)d_out;

  // 1. prep: 6 weight transposes + 3 activation converts
  PrepJobs pj;
  const float* psrc[9] = { Wq, Wsk, Wtk, Wsv, Wtv, Wo, query, src, trg };
  unsigned short* pdst[9] = { WqT, WsT, WtT, WsvT, WtvT, WoT, queryB, srcB, trgB };
  int pK[9]    = { 512, 2048, 2048, 2048, 2048, 1536, 512, 2048, 2048 };
  int ptype[9] = { 0, 0, 0, 0, 0, 0, 1, 1, 1 };
  int prows[9] = { 0, 0, 0, 0, 0, 0, 4096, 1152, 1152 };
  int pbase = 0;
  for (int i = 0; i < 9; ++i) {
    pj.src[i] = psrc[i]; pj.dst[i] = pdst[i]; pj.K[i] = pK[i]; pj.type[i] = ptype[i];
    pj.base[i] = pbase;
    pbase += ptype[i] ? (prows[i] / 64) * (pK[i] / 64) : (pK[i] / 64) * 8;
  }
  prep<<<pbase, 256, 0, stream>>>(pj);

  // 2. merged projections (2,4)=64x128 tiles, A-in-regs, 800 blocks:
  //    s_key, t_key (mode 0) | s_val, t_val (mode 2, A-format) | qh, Pb (mode 0)
  {
    PBatch pb;
    int base = 0;
    const unsigned short* Aarr[4] = { srcB, trgB, srcB, trgB };
    const unsigned short* Barr[4] = { WsT, WtT, WsvT, WtvT };
    const float* biasArr[4] = { bs, bt, bsv, btv };
    unsigned short* Carr[4] = { s_key, t_key, s_val, t_val };
    for (int i = 0; i < 4; ++i) {     // 4 big K=2048 jobs: 18 m x 4 n = 72 tiles
      PJob& j = pb.j[i];
      j.A0 = Aarr[i]; j.Bt = Barr[i]; j.bias = biasArr[i]; j.Cb = Carr[i];
      j.Astride = 2048; j.Bstride = 2048; j.Cstride = 512;
      j.nTilesN = 4; j.nt = 32; j.mode = (i < 2) ? 0 : 2;
      j.tileBase = base; base += 18 * 4;
    }
    {                                  // qh = query@Wq + bq: 64x4 = 256 tiles
      PJob& j = pb.j[4];
      j.A0 = queryB; j.Bt = WqT; j.bias = bq; j.Cb = qh;
      j.Astride = 512; j.Bstride = 512; j.Cstride = 512;
      j.nTilesN = 4; j.nt = 8; j.mode = 0;
      j.tileBase = base; base += 64 * 4;
    }
    {                                  // Pb = query@Wo1 + bo: 256 tiles
      PJob& j = pb.j[5];
      j.A0 = queryB; j.Bt = WoT; j.bias = bo; j.Cb = Pb;
      j.Astride = 512; j.Bstride = 1536; j.Cstride = 512;
      j.nTilesN = 4; j.nt = 8; j.mode = 0;
      j.tileBase = base; base += 64 * 4;
    }
    pb.j[6] = pb.j[5]; pb.j[6].tileBase = 0x7fffffff;
    pb.njobs = 6;
    gemm_areg<<<base, 256, 0, stream>>>(pb);   // 800 blocks
  }

  // 3. stage3: svgemm (288 blocks) + scores/softmax (256 blocks) = 544 blocks
  {
    S3Args sa;
    HJob& a = sa.g[0];
    a.A0 = s_val; a.Bt = WoT + 512; a.Cb = svp;
    a.Astride = 512; a.Bstride = 1536; a.Cstride = 512;
    a.nTilesN = 8; a.nt = 8; a.tileBase = 0;
    HJob& b2 = sa.g[1];
    b2 = a;
    b2.A0 = t_val; b2.Bt = WoT + 1024; b2.Cb = tvp;
    b2.tileBase = 18 * 8;       // 144
    sa.nGemm = 288;
    sa.qh = qh; sa.s_key = s_key; sa.t_key = t_key;
    sa.Wsw = Wsw; sa.Wtw = Wtw;
    stage3<<<288 + 256, 256, 0, stream>>>(sa);
  }

  // 4. weighted sum + Pb + relu -> out (512 blocks, h-split)
  wsum<<<dim3(32, 8, 2), 256, 0, stream>>>(Wsw, Wtw, svp, tvp, Pb, out);
}

// Round 17
// 73.104 us; speedup vs baseline: 1.0778x; 1.0778x over previous
//
#include <hip/hip_runtime.h>
#include <hip/hip_bf16.h>
#include <math.h>

#define DEVI __device__ __forceinline__

typedef __attribute__((ext_vector_type(4))) float f32x4;
typedef __attribute__((ext_vector_type(8))) short bf16x8;

DEVI unsigned short f2bf(float f) {
  union { float f; unsigned int u; } v; v.f = f;
  return (unsigned short)((v.u + 0x7FFFu + ((v.u >> 16) & 1u)) >> 16);
}
DEVI float bf2f(unsigned short s) {
  union { unsigned int u; float f; } v; v.u = ((unsigned int)s) << 16; return v.f;
}
DEVI bf16x8 pack8(f32x4 a, f32x4 b) {
  bf16x8 r;
  r[0] = (short)f2bf(a[0]); r[1] = (short)f2bf(a[1]);
  r[2] = (short)f2bf(a[2]); r[3] = (short)f2bf(a[3]);
  r[4] = (short)f2bf(b[0]); r[5] = (short)f2bf(b[1]);
  r[6] = (short)f2bf(b[2]); r[7] = (short)f2bf(b[3]);
  return r;
}
DEVI void gload16(const unsigned short* g, unsigned short* l) {
  __builtin_amdgcn_global_load_lds(
      (const __attribute__((address_space(1))) unsigned int*)g,
      (__attribute__((address_space(3))) unsigned int*)l, 16, 0, 0);
}
// raw workgroup barrier WITHOUT the implicit vmcnt(0) drain of __syncthreads
#define SBAR() do { asm volatile("" ::: "memory"); \
                    __builtin_amdgcn_s_barrier();  \
                    asm volatile("" ::: "memory"); } while (0)

// ==== prep: weights f32[K][512] -> bf16 [512][K] swz ; f32[M][K] -> bf16 [M][K] swz
// swizzle: within each 64-elem k-group, kblock kb of row n stored at ((kb+n)&7).
struct PrepJobs {
  const float* src[9];
  unsigned short* dst[9];
  int K[9];
  int base[9];
  int type[9];   // 0 = weight transpose (64x64 tiles), 1 = row-major convert
};

__global__ __launch_bounds__(256) void prep(PrepJobs J) {
  __shared__ float t[64][65];   // 16.6 KB
  int tile = blockIdx.x;
  int job = 0;
  while (job < 8 && tile >= J.base[job + 1]) ++job;
  int tl = tile - J.base[job];
  int K = J.K[job];
  if (J.type[job] == 0) {
    int tn = tl & 7, tk = tl >> 3;   // 512/64 = 8 n-tiles
    int x = threadIdx.x & 63, y = threadIdx.x >> 6;
    const float* s = J.src[job];
    int k0 = tk * 64, n0 = tn * 64;
#pragma unroll
    for (int yy = y; yy < 64; yy += 4)
      t[yy][x] = s[(size_t)(k0 + yy) * 512 + n0 + x];
    __syncthreads();
    unsigned short* d = J.dst[job];
    int kb = (x >> 3) & 7, ko = x & 7;   // k = k0 + x, k0 % 64 == 0
#pragma unroll
    for (int yy = y; yy < 64; yy += 4) {
      int n = n0 + yy;
      int kswz = k0 + (((kb + n) & 7) << 3) + ko;
      d[(size_t)n * K + kswz] = f2bf(t[x][yy]);
    }
  } else {
    int nk = K >> 6;
    int rt = tl / nk;
    int r0 = rt * 64, k0 = (tl - rt * nk) * 64;
    int r = threadIdx.x >> 2, kq = threadIdx.x & 3;
    int row = r0 + r;
    const float* s = J.src[job] + (size_t)row * K + k0 + kq * 16;
    f32x4 a0 = *(const f32x4*)s;
    f32x4 a1 = *(const f32x4*)(s + 4);
    f32x4 a2 = *(const f32x4*)(s + 8);
    f32x4 a3 = *(const f32x4*)(s + 12);
    unsigned short* d = J.dst[job] + (size_t)row * K + k0;
    int kb0 = kq * 2;
    *(bf16x8*)(d + ((kb0 + row) & 7) * 8) = pack8(a0, a1);
    *(bf16x8*)(d + ((kb0 + 1 + row) & 7) * 8) = pack8(a2, a3);
  }
}

// ==== MFMA GEMM, counted-vmcnt double-buffer, (2,4)=64x128 tile ============
// 4 waves (2m x 2n), wave tile 32x64. A/B bf16 pre-swizzled; staging is pure
// global_load_lds DMA; s_waitcnt vmcnt(6) keeps next tile in flight.
// mode 0: bf16 row-major out. mode 2: bf16 out with per-row k-group swizzle
// (so C can be consumed as an A/B operand by a later GEMM).
struct GJob {
  const unsigned short* A0;
  const unsigned short* Bt;
  const float* bias;        // may be nullptr
  unsigned short* Cb;
  int Astride, Bstride, Cstride, nTilesN, nt, mode, tileBase;
};
struct GBatch { GJob j[7]; int njobs; int swz; };

template <int MI, int NI>
__global__ __launch_bounds__(256) void gemm_pipe(GBatch batch) {
  constexpr int BM = MI * 32, BN = NI * 32;
  int gt = blockIdx.x;
  if (batch.swz) {
    int cpx = gridDim.x >> 3;
    gt = (blockIdx.x & 7) * cpx + (blockIdx.x >> 3);
  }
  int job = 0;
#pragma unroll
  for (int i = 1; i < 7; ++i)
    if (i < batch.njobs && gt >= batch.j[i].tileBase) job = i;
  GJob J = batch.j[job];
  int tl = gt - J.tileBase;
  int bm = (tl / J.nTilesN) * BM, bn = (tl % J.nTilesN) * BN;

  __shared__ __align__(16) unsigned short La[2][BM * 64];
  __shared__ __align__(16) unsigned short Lb[2][BN * 64];

  int tid = threadIdx.x;
  int wave = tid >> 6, lane = tid & 63;
  int lrow = lane & 15, lq = lane >> 4;
  int wr = (wave >> 1) * (MI * 16), wc = (wave & 1) * (NI * 16);
  f32x4 acc[MI][NI] = {};

  int nt = J.nt;

  auto stage_both = [&](int t, int buf) {
    const unsigned short* GA = J.A0 + (size_t)bm * J.Astride + (size_t)(t << 6);
    const unsigned short* GB = J.Bt + (size_t)bn * J.Bstride + (size_t)(t << 6);
#pragma unroll
    for (int p = 0; p < MI; ++p) {
      int s = p * 256 + tid;
      gload16(GA + (size_t)(s >> 3) * J.Astride + (s & 7) * 8,
              &La[buf][(size_t)(p * 256 + wave * 64) * 8]);
    }
#pragma unroll
    for (int p = 0; p < NI; ++p) {
      int s = p * 256 + tid;
      gload16(GB + (size_t)(s >> 3) * J.Bstride + (s & 7) * 8,
              &Lb[buf][(size_t)(p * 256 + wave * 64) * 8]);
    }
  };

  stage_both(0, 0);
  if (nt > 1) stage_both(1, 1);

  for (int t = 0; t < nt; ++t) {
    if (t + 1 < nt) {
      if constexpr (MI + NI == 8)      asm volatile("s_waitcnt vmcnt(8)" ::: "memory");
      else if constexpr (MI + NI == 6) asm volatile("s_waitcnt vmcnt(6)" ::: "memory");
      else                             asm volatile("s_waitcnt vmcnt(4)" ::: "memory");
    } else {
      asm volatile("s_waitcnt vmcnt(0)" ::: "memory");
    }
    SBAR();
    int cur = t & 1;
#pragma unroll
    for (int kc = 0; kc < 2; ++kc) {
      int kb = kc * 4 + lq;
      bf16x8 af[MI], bv[NI];
#pragma unroll
      for (int mi = 0; mi < MI; ++mi) {
        int r = wr + mi * 16 + lrow;
        af[mi] = *(const bf16x8*)&La[cur][r * 64 + ((kb + r) & 7) * 8];
      }
#pragma unroll
      for (int ni = 0; ni < NI; ++ni) {
        int r = wc + ni * 16 + lrow;
        bv[ni] = *(const bf16x8*)&Lb[cur][r * 64 + ((kb + r) & 7) * 8];
      }
#pragma unroll
      for (int mi = 0; mi < MI; ++mi)
#pragma unroll
        for (int ni = 0; ni < NI; ++ni)
          acc[mi][ni] = __builtin_amdgcn_mfma_f32_16x16x32_bf16(af[mi], bv[ni], acc[mi][ni], 0, 0, 0);
    }
    SBAR();
    if (t + 2 < nt) stage_both(t + 2, cur);
  }

  // epilogue: C/D layout col=lane&15, row=lq*4+reg
#pragma unroll
  for (int mi = 0; mi < MI; ++mi) {
#pragma unroll
    for (int ni = 0; ni < NI; ++ni) {
      int gn = bn + wc + ni * 16 + lrow;
      float bvs = J.bias ? J.bias[gn] : 0.f;
      int gm0 = bm + wr + mi * 16 + lq * 4;
      if (J.mode == 0) {
#pragma unroll
        for (int r = 0; r < 4; ++r)
          J.Cb[(size_t)(gm0 + r) * J.Cstride + gn] = f2bf(acc[mi][ni][r] + bvs);
      } else {
        // mode 2: store so row-major [M][N] reads as a swizzled GEMM operand
#pragma unroll
        for (int r = 0; r < 4; ++r) {
          int row = gm0 + r;
          int col = (gn & ~63) | (((((gn >> 3) & 7) + row) & 7) << 3) | (gn & 7);
          J.Cb[(size_t)row * J.Cstride + col] = f2bf(acc[mi][ni][r] + bvs);
        }
      }
    }
  }
}

// ==== stage3: hybrid svgemm (blocks < nGemm) + scores/softmax (rest) ========
struct HJob {
  const unsigned short* A0;
  const unsigned short* Bt;
  unsigned short* Cb;
  int Astride, Bstride, Cstride, nTilesN, nt, tileBase;
};
struct S3Args {
  HJob g[2];
  int nGemm;                 // gemm blocks count (288)
  const unsigned short* qh;
  const unsigned short* s_key;
  const unsigned short* t_key;
  float* Wsw;
  float* Wtw;
};

__global__ __launch_bounds__(256) void stage3(S3Args A) {
  __shared__ __align__(16) unsigned char smem[16384];
  int tid = threadIdx.x;
  int wave = tid >> 6, lane = tid & 63;
  int lrow = lane & 15, lq = lane >> 4;

  if ((int)blockIdx.x < A.nGemm) {
    // ---- (2,2) 64x64 GEMM, pure-DMA double buffer, counted vmcnt ----
    int gt = blockIdx.x;
    HJob J = (gt >= A.g[1].tileBase) ? A.g[1] : A.g[0];
    int tl = gt - J.tileBase;
    int bm = (tl / J.nTilesN) * 64, bn = (tl % J.nTilesN) * 64;
    int wr = (wave >> 1) * 32, wc = (wave & 1) * 32;
    f32x4 acc[2][2] = {};
    int nt = J.nt;

    __shared__ __align__(16) unsigned short Lg[2][4096 + 4096];  // 32 KB
    auto stage2 = [&](int t, int buf) {
      const unsigned short* GA = J.A0 + (size_t)bm * J.Astride + (size_t)(t << 6);
      const unsigned short* GB = J.Bt + (size_t)bn * J.Bstride + (size_t)(t << 6);
#pragma unroll
      for (int p = 0; p < 2; ++p) {
        int s = p * 256 + tid;
        gload16(GA + (size_t)(s >> 3) * J.Astride + (s & 7) * 8,
                &Lg[buf][(size_t)(p * 256 + wave * 64) * 8]);
      }
#pragma unroll
      for (int p = 0; p < 2; ++p) {
        int s = p * 256 + tid;
        gload16(GB + (size_t)(s >> 3) * J.Bstride + (s & 7) * 8,
                &Lg[buf][4096 + (size_t)(p * 256 + wave * 64) * 8]);
      }
    };

    stage2(0, 0);
    if (nt > 1) stage2(1, 1);

    for (int t = 0; t < nt; ++t) {
      if (t + 1 < nt) asm volatile("s_waitcnt vmcnt(4)" ::: "memory");
      else            asm volatile("s_waitcnt vmcnt(0)" ::: "memory");
      SBAR();
      int cur = t & 1;
#pragma unroll
      for (int kc = 0; kc < 2; ++kc) {
        int kb = kc * 4 + lq;
        bf16x8 af[2], bv[2];
#pragma unroll
        for (int mi = 0; mi < 2; ++mi) {
          int r = wr + mi * 16 + lrow;
          af[mi] = *(const bf16x8*)&Lg[cur][r * 64 + ((kb + r) & 7) * 8];
        }
#pragma unroll
        for (int ni = 0; ni < 2; ++ni) {
          int r = wc + ni * 16 + lrow;
          bv[ni] = *(const bf16x8*)&Lg[cur][4096 + r * 64 + ((kb + r) & 7) * 8];
        }
#pragma unroll
        for (int mi = 0; mi < 2; ++mi)
#pragma unroll
          for (int ni = 0; ni < 2; ++ni)
            acc[mi][ni] = __builtin_amdgcn_mfma_f32_16x16x32_bf16(af[mi], bv[ni], acc[mi][ni], 0, 0, 0);
      }
      SBAR();
      if (t + 2 < nt) stage2(t + 2, cur);
    }
#pragma unroll
    for (int mi = 0; mi < 2; ++mi) {
#pragma unroll
      for (int ni = 0; ni < 2; ++ni) {
        int gn = bn + wc + ni * 16 + lrow;
        int gm0 = bm + wr + mi * 16 + lq * 4;
#pragma unroll
        for (int r = 0; r < 4; ++r)
          J.Cb[(size_t)(gm0 + r) * J.Cstride + gn] = f2bf(acc[mi][ni][r]);
      }
    }
  } else {
    // ---- scores + separable softmax -> Wsw/Wtw (f32 global) ----
    float (*red)[3][64][4] = (float(*)[3][64][4])smem;   // 12 KB
    int bid2 = blockIdx.x - A.nGemm;
    int b = bid2 >> 3, lc = bid2 & 7;
    int mat = wave >> 1, kh = wave & 1;
    int row0 = b * 128 + lc * 16;
    const unsigned short* qp = A.qh + (size_t)row0 * 512;
    const unsigned short* key = (mat ? A.s_key : A.t_key) + (size_t)b * 36 * 512;
    f32x4 acc[3] = {};
    for (int kc = kh * 8; kc < kh * 8 + 8; ++kc) {
      int k = kc * 32 + lq * 8;
      bf16x8 af = *(const bf16x8*)(qp + (size_t)lrow * 512 + k);
#pragma unroll
      for (int nf = 0; nf < 3; ++nf) {
        int n = nf * 16 + lrow; if (n > 35) n = 35;   // clamp; masked below
        bf16x8 bv = *(const bf16x8*)(key + (size_t)n * 512 + k);
        acc[nf] = __builtin_amdgcn_mfma_f32_16x16x32_bf16(af, bv, acc[nf], 0, 0, 0);
      }
    }
#pragma unroll
    for (int nf = 0; nf < 3; ++nf)
      *(f32x4*)&red[wave][nf][lane][0] = acc[nf];
    __syncthreads();

    if (kh == 0) {     // waves 0 (mat0 -> Wsw) and 2 (mat1 -> Wtw)
      const float ccs = 0.022097086912079608f;   // 0.5 / sqrt(512)
      float ex[3][4];
#pragma unroll
      for (int r = 0; r < 4; ++r) {
        float a0 = (red[wave][0][lane][r] + red[wave + 1][0][lane][r]) * ccs;
        float a1 = (red[wave][1][lane][r] + red[wave + 1][1][lane][r]) * ccs;
        float a2 = (lrow < 4)
            ? (red[wave][2][lane][r] + red[wave + 1][2][lane][r]) * ccs : -1e30f;
        float mx = fmaxf(fmaxf(a0, a1), a2);
        for (int s = 1; s < 16; s <<= 1) mx = fmaxf(mx, __shfl_xor(mx, s));
        float e0 = __expf(a0 - mx), e1 = __expf(a1 - mx);
        float e2 = (lrow < 4) ? __expf(a2 - mx) : 0.f;
        float sum = e0 + e1 + e2;
        for (int s = 1; s < 16; s <<= 1) sum += __shfl_xor(sum, s);
        float inv = 1.f / sum;
        ex[0][r] = e0 * inv; ex[1][r] = e1 * inv; ex[2][r] = e2 * inv;
      }
      float* W = mat ? A.Wtw : A.Wsw;
#pragma unroll
      for (int nf = 0; nf < 3; ++nf) {
        int col = nf * 16 + lrow;
        if (col < 36) {
#pragma unroll
          for (int r = 0; r < 4; ++r)
            W[(size_t)(row0 + lq * 4 + r) * 36 + col] = ex[nf][r];
        }
      }
    }
  }
}

// ==== wsum: out = relu(Pb + ws@svp + wt@tvp), 16 l-rows per block ==========
__global__ __launch_bounds__(256) void wsum(
    const float* __restrict__ Wsw, const float* __restrict__ Wtw,
    const unsigned short* __restrict__ svp, const unsigned short* __restrict__ tvp,
    const unsigned short* __restrict__ Pb, float* __restrict__ out) {
  __shared__ float wlT[2][36][16];   // 4.6 KB
  int b = blockIdx.x, lc = blockIdx.y;
  int tid = threadIdx.x;
  int row0 = b * 128 + lc * 16;
  for (int i = tid; i < 2 * 16 * 36; i += 256) {
    int m = i / 576, rem = i - m * 576;
    int l = rem / 36, j = rem - l * 36;
    wlT[m][j][l] = (m ? Wtw : Wsw)[(size_t)(row0 + l) * 36 + j];
  }
  __syncthreads();

  int lgrp = tid >> 6, hgrp = tid & 63;
  float a2[4][8] = {};
#pragma unroll
  for (int m = 0; m < 2; ++m) {
    const unsigned short* V = (m ? tvp : svp) + (size_t)b * 36 * 512;
    for (int j = 0; j < 36; ++j) {
      f32x4 wa = *(const f32x4*)&wlT[m][j][lgrp * 4];
      bf16x8 v = *(const bf16x8*)(V + (size_t)j * 512 + hgrp * 8);
      float vf[8];
#pragma unroll
      for (int hi = 0; hi < 8; ++hi) vf[hi] = bf2f((unsigned short)v[hi]);
#pragma unroll
      for (int li = 0; li < 4; ++li)
#pragma unroll
        for (int hi = 0; hi < 8; ++hi) a2[li][hi] += wa[li] * vf[hi];
    }
  }
#pragma unroll
  for (int li = 0; li < 4; ++li) {
    int R = row0 + lgrp * 4 + li;
    bf16x8 p = *(const bf16x8*)(Pb + (size_t)R * 512 + hgrp * 8);
    float* op = out + (size_t)R * 512 + hgrp * 8;
    f32x4 o0, o1;
#pragma unroll
    for (int hi = 0; hi < 4; ++hi) {
      o0[hi] = fmaxf(bf2f((unsigned short)p[hi]) + a2[li][hi], 0.f);
      o1[hi] = fmaxf(bf2f((unsigned short)p[4 + hi]) + a2[li][4 + hi], 0.f);
    }
    *(f32x4*)op = o0;
    *(f32x4*)(op + 4) = o1;
  }
}

// ---------------------------------------------------------------------------
extern "C" void kernel_launch(void* const* d_in, const int* in_sizes, int n_in,
                              void* d_out, int out_size, void* d_ws, size_t ws_size,
                              hipStream_t stream) {
  (void)in_sizes; (void)n_in; (void)out_size; (void)ws_size;
  const float* query = (const float*)d_in[0];
  const float* src   = (const float*)d_in[1];
  const float* trg   = (const float*)d_in[2];
  const float* Wq  = (const float*)d_in[3];  const float* bq  = (const float*)d_in[4];
  const float* Wsk = (const float*)d_in[5];  const float* bs  = (const float*)d_in[6];
  const float* Wtk = (const float*)d_in[7];  const float* bt  = (const float*)d_in[8];
  const float* Wsv = (const float*)d_in[9];  const float* bsv = (const float*)d_in[10];
  const float* Wtv = (const float*)d_in[11]; const float* btv = (const float*)d_in[12];
  const float* Wo  = (const float*)d_in[13]; const float* bo  = (const float*)d_in[14];

  // workspace (bf16 shorts unless noted) ~38 MB
  unsigned short* WqT    = (unsigned short*)d_ws;     // 512*512
  unsigned short* WsT    = WqT  + 512 * 512;          // 512*2048
  unsigned short* WtT    = WsT  + 512 * 2048;
  unsigned short* WsvT   = WtT  + 512 * 2048;
  unsigned short* WtvT   = WsvT + 512 * 2048;
  unsigned short* WoT    = WtvT + 512 * 2048;         // 512*1536
  unsigned short* queryB = WoT  + 512 * 1536;         // 4096*512 swz
  unsigned short* srcB   = queryB + 4096 * 512;       // 1152*2048 swz
  unsigned short* trgB   = srcB + 1152 * 2048;
  unsigned short* qh     = trgB + 1152 * 2048;        // 4096*512 plain
  unsigned short* s_key  = qh + 4096 * 512;           // 1152*512 plain
  unsigned short* t_key  = s_key + 1152 * 512;
  unsigned short* s_val  = t_key + 1152 * 512;        // 1152*512 A-swz (mode 2)
  unsigned short* t_val  = s_val + 1152 * 512;
  unsigned short* svp    = t_val + 1152 * 512;        // 1152*512 plain
  unsigned short* tvp    = svp + 1152 * 512;
  unsigned short* Pb     = tvp + 1152 * 512;          // 4096*512 plain
  float* Wsw = (float*)(Pb + 4096 * 512);             // 4096*36 f32
  float* Wtw = Wsw + 4096 * 36;
  float* out = (float*)d_out;

  // 1. prep: 6 weight transposes + 3 activation converts
  PrepJobs pj;
  const float* psrc[9] = { Wq, Wsk, Wtk, Wsv, Wtv, Wo, query, src, trg };
  unsigned short* pdst[9] = { WqT, WsT, WtT, WsvT, WtvT, WoT, queryB, srcB, trgB };
  int pK[9]    = { 512, 2048, 2048, 2048, 2048, 1536, 512, 2048, 2048 };
  int ptype[9] = { 0, 0, 0, 0, 0, 0, 1, 1, 1 };
  int prows[9] = { 0, 0, 0, 0, 0, 0, 4096, 1152, 1152 };
  int pbase = 0;
  for (int i = 0; i < 9; ++i) {
    pj.src[i] = psrc[i]; pj.dst[i] = pdst[i]; pj.K[i] = pK[i]; pj.type[i] = ptype[i];
    pj.base[i] = pbase;
    pbase += ptype[i] ? (prows[i] / 64) * (pK[i] / 64) : (pK[i] / 64) * 8;
  }
  prep<<<pbase, 256, 0, stream>>>(pj);

  // 2. merged projections (2,4)=64x128 tiles, 800 blocks:
  //    s_key, t_key (mode 0) | s_val, t_val (mode 2, A-format) | qh, Pb (mode 0)
  {
    GBatch pb;
    pb.swz = 0;
    int base = 0;
    const unsigned short* Aarr[4] = { srcB, trgB, srcB, trgB };
    const unsigned short* Barr[4] = { WsT, WtT, WsvT, WtvT };
    const float* biasArr[4] = { bs, bt, bsv, btv };
    unsigned short* Carr[4] = { s_key, t_key, s_val, t_val };
    for (int i = 0; i < 4; ++i) {     // 4 big K=2048 jobs: 18 m x 4 n = 72 tiles
      GJob& j = pb.j[i];
      j.A0 = Aarr[i]; j.Bt = Barr[i]; j.bias = biasArr[i]; j.Cb = Carr[i];
      j.Astride = 2048; j.Bstride = 2048; j.Cstride = 512;
      j.nTilesN = 4; j.nt = 32; j.mode = (i < 2) ? 0 : 2;
      j.tileBase = base; base += 18 * 4;
    }
    {                                  // qh = query@Wq + bq: 64x4 = 256 tiles
      GJob& j = pb.j[4];
      j.A0 = queryB; j.Bt = WqT; j.bias = bq; j.Cb = qh;
      j.Astride = 512; j.Bstride = 512; j.Cstride = 512;
      j.nTilesN = 4; j.nt = 8; j.mode = 0;
      j.tileBase = base; base += 64 * 4;
    }
    {                                  // Pb = query@Wo1 + bo: 256 tiles
      GJob& j = pb.j[5];
      j.A0 = queryB; j.Bt = WoT; j.bias = bo; j.Cb = Pb;
      j.Astride = 512; j.Bstride = 1536; j.Cstride = 512;
      j.nTilesN = 4; j.nt = 8; j.mode = 0;
      j.tileBase = base; base += 64 * 4;
    }
    pb.j[6] = pb.j[5]; pb.j[6].tileBase = 0x7fffffff;
    pb.njobs = 6;
    gemm_pipe<2, 4><<<base, 256, 0, stream>>>(pb);   // 800 blocks
  }

  // 3. stage3: svgemm (288 blocks) + scores/softmax (256 blocks) = 544 blocks
  {
    S3Args sa;
    HJob& a = sa.g[0];
    a.A0 = s_val; a.Bt = WoT + 512; a.Cb = svp;
    a.Astride = 512; a.Bstride = 1536; a.Cstride = 512;
    a.nTilesN = 8; a.nt = 8; a.tileBase = 0;
    HJob& b2 = sa.g[1];
    b2 = a;
    b2.A0 = t_val; b2.Bt = WoT + 1024; b2.Cb = tvp;
    b2.tileBase = 18 * 8;       // 144
    sa.nGemm = 288;
    sa.qh = qh; sa.s_key = s_key; sa.t_key = t_key;
    sa.Wsw = Wsw; sa.Wtw = Wtw;
    stage3<<<288 + 256, 256, 0, stream>>>(sa);
  }

  // 4. weighted sum + Pb + relu -> out (256 blocks)
  wsum<<<dim3(32, 8), 256, 0, stream>>>(Wsw, Wtw, svp, tvp, Pb, out);
}

// Round 18
// 72.843 us; speedup vs baseline: 1.0816x; 1.0036x over previous
//
#include <hip/hip_runtime.h>
#include <hip/hip_bf16.h>
#include <math.h>

#define DEVI __device__ __forceinline__

typedef __attribute__((ext_vector_type(4))) float f32x4;
typedef __attribute__((ext_vector_type(8))) short bf16x8;

DEVI unsigned short f2bf(float f) {
  union { float f; unsigned int u; } v; v.f = f;
  return (unsigned short)((v.u + 0x7FFFu + ((v.u >> 16) & 1u)) >> 16);
}
DEVI float bf2f(unsigned short s) {
  union { unsigned int u; float f; } v; v.u = ((unsigned int)s) << 16; return v.f;
}
DEVI bf16x8 pack8(f32x4 a, f32x4 b) {
  bf16x8 r;
  r[0] = (short)f2bf(a[0]); r[1] = (short)f2bf(a[1]);
  r[2] = (short)f2bf(a[2]); r[3] = (short)f2bf(a[3]);
  r[4] = (short)f2bf(b[0]); r[5] = (short)f2bf(b[1]);
  r[6] = (short)f2bf(b[2]); r[7] = (short)f2bf(b[3]);
  return r;
}
DEVI void gload16(const unsigned short* g, unsigned short* l) {
  __builtin_amdgcn_global_load_lds(
      (const __attribute__((address_space(1))) unsigned int*)g,
      (__attribute__((address_space(3))) unsigned int*)l, 16, 0, 0);
}
// raw workgroup barrier WITHOUT the implicit vmcnt(0) drain of __syncthreads
#define SBAR() do { asm volatile("" ::: "memory"); \
                    __builtin_amdgcn_s_barrier();  \
                    asm volatile("" ::: "memory"); } while (0)

// ==== prep: weights f32[K][512] -> bf16 [512][K] swz ; f32[M][K] -> bf16 [M][K] swz
// swizzle: within each 64-elem k-group, kblock kb of row n stored at ((kb+n)&7).
struct PrepJobs {
  const float* src[9];
  unsigned short* dst[9];
  int K[9];
  int base[9];
  int type[9];   // 0 = weight transpose (64x64 tiles), 1 = row-major convert
};

__global__ __launch_bounds__(256) void prep(PrepJobs J) {
  __shared__ float t[64][65];   // 16.6 KB
  int tile = blockIdx.x;
  int job = 0;
  while (job < 8 && tile >= J.base[job + 1]) ++job;
  int tl = tile - J.base[job];
  int K = J.K[job];
  if (J.type[job] == 0) {
    int tn = tl & 7, tk = tl >> 3;   // 512/64 = 8 n-tiles
    int x = threadIdx.x & 63, y = threadIdx.x >> 6;
    const float* s = J.src[job];
    int k0 = tk * 64, n0 = tn * 64;
#pragma unroll
    for (int yy = y; yy < 64; yy += 4)
      t[yy][x] = s[(size_t)(k0 + yy) * 512 + n0 + x];
    __syncthreads();
    unsigned short* d = J.dst[job];
    int kb = (x >> 3) & 7, ko = x & 7;   // k = k0 + x, k0 % 64 == 0
#pragma unroll
    for (int yy = y; yy < 64; yy += 4) {
      int n = n0 + yy;
      int kswz = k0 + (((kb + n) & 7) << 3) + ko;
      d[(size_t)n * K + kswz] = f2bf(t[x][yy]);
    }
  } else {
    int nk = K >> 6;
    int rt = tl / nk;
    int r0 = rt * 64, k0 = (tl - rt * nk) * 64;
    int r = threadIdx.x >> 2, kq = threadIdx.x & 3;
    int row = r0 + r;
    const float* s = J.src[job] + (size_t)row * K + k0 + kq * 16;
    f32x4 a0 = *(const f32x4*)s;
    f32x4 a1 = *(const f32x4*)(s + 4);
    f32x4 a2 = *(const f32x4*)(s + 8);
    f32x4 a3 = *(const f32x4*)(s + 12);
    unsigned short* d = J.dst[job] + (size_t)row * K + k0;
    int kb0 = kq * 2;
    *(bf16x8*)(d + ((kb0 + row) & 7) * 8) = pack8(a0, a1);
    *(bf16x8*)(d + ((kb0 + 1 + row) & 7) * 8) = pack8(a2, a3);
  }
}

// ==== MFMA GEMM, counted-vmcnt double-buffer, (2,4)=64x128 tile ============
// 4 waves (2m x 2n), wave tile 32x64. A/B bf16 pre-swizzled; staging is pure
// global_load_lds DMA; s_waitcnt vmcnt(6) keeps next tile in flight.
// mode 0: bf16 row-major out. mode 2: bf16 out with per-row k-group swizzle
// (so C can be consumed as an A/B operand by a later GEMM).
struct GJob {
  const unsigned short* A0;
  const unsigned short* Bt;
  const float* bias;        // may be nullptr
  unsigned short* Cb;
  int Astride, Bstride, Cstride, nTilesN, nt, mode, tileBase;
};
struct GBatch { GJob j[7]; int njobs; int swz; };

template <int MI, int NI>
__global__ __launch_bounds__(256) void gemm_pipe(GBatch batch) {
  constexpr int BM = MI * 32, BN = NI * 32;
  int gt = blockIdx.x;
  if (batch.swz) {
    int cpx = gridDim.x >> 3;
    gt = (blockIdx.x & 7) * cpx + (blockIdx.x >> 3);
  }
  int job = 0;
#pragma unroll
  for (int i = 1; i < 7; ++i)
    if (i < batch.njobs && gt >= batch.j[i].tileBase) job = i;
  GJob J = batch.j[job];
  int tl = gt - J.tileBase;
  int bm = (tl / J.nTilesN) * BM, bn = (tl % J.nTilesN) * BN;

  __shared__ __align__(16) unsigned short La[2][BM * 64];
  __shared__ __align__(16) unsigned short Lb[2][BN * 64];

  int tid = threadIdx.x;
  int wave = tid >> 6, lane = tid & 63;
  int lrow = lane & 15, lq = lane >> 4;
  int wr = (wave >> 1) * (MI * 16), wc = (wave & 1) * (NI * 16);
  f32x4 acc[MI][NI] = {};

  int nt = J.nt;

  auto stage_both = [&](int t, int buf) {
    const unsigned short* GA = J.A0 + (size_t)bm * J.Astride + (size_t)(t << 6);
    const unsigned short* GB = J.Bt + (size_t)bn * J.Bstride + (size_t)(t << 6);
#pragma unroll
    for (int p = 0; p < MI; ++p) {
      int s = p * 256 + tid;
      gload16(GA + (size_t)(s >> 3) * J.Astride + (s & 7) * 8,
              &La[buf][(size_t)(p * 256 + wave * 64) * 8]);
    }
#pragma unroll
    for (int p = 0; p < NI; ++p) {
      int s = p * 256 + tid;
      gload16(GB + (size_t)(s >> 3) * J.Bstride + (s & 7) * 8,
              &Lb[buf][(size_t)(p * 256 + wave * 64) * 8]);
    }
  };

  stage_both(0, 0);
  if (nt > 1) stage_both(1, 1);

  for (int t = 0; t < nt; ++t) {
    if (t + 1 < nt) {
      if constexpr (MI + NI == 8)      asm volatile("s_waitcnt vmcnt(8)" ::: "memory");
      else if constexpr (MI + NI == 6) asm volatile("s_waitcnt vmcnt(6)" ::: "memory");
      else                             asm volatile("s_waitcnt vmcnt(4)" ::: "memory");
    } else {
      asm volatile("s_waitcnt vmcnt(0)" ::: "memory");
    }
    SBAR();
    int cur = t & 1;
#pragma unroll
    for (int kc = 0; kc < 2; ++kc) {
      int kb = kc * 4 + lq;
      bf16x8 af[MI], bv[NI];
#pragma unroll
      for (int mi = 0; mi < MI; ++mi) {
        int r = wr + mi * 16 + lrow;
        af[mi] = *(const bf16x8*)&La[cur][r * 64 + ((kb + r) & 7) * 8];
      }
#pragma unroll
      for (int ni = 0; ni < NI; ++ni) {
        int r = wc + ni * 16 + lrow;
        bv[ni] = *(const bf16x8*)&Lb[cur][r * 64 + ((kb + r) & 7) * 8];
      }
#pragma unroll
      for (int mi = 0; mi < MI; ++mi)
#pragma unroll
        for (int ni = 0; ni < NI; ++ni)
          acc[mi][ni] = __builtin_amdgcn_mfma_f32_16x16x32_bf16(af[mi], bv[ni], acc[mi][ni], 0, 0, 0);
    }
    SBAR();
    if (t + 2 < nt) stage_both(t + 2, cur);
  }

  // epilogue: C/D layout col=lane&15, row=lq*4+reg
#pragma unroll
  for (int mi = 0; mi < MI; ++mi) {
#pragma unroll
    for (int ni = 0; ni < NI; ++ni) {
      int gn = bn + wc + ni * 16 + lrow;
      float bvs = J.bias ? J.bias[gn] : 0.f;
      int gm0 = bm + wr + mi * 16 + lq * 4;
      if (J.mode == 0) {
#pragma unroll
        for (int r = 0; r < 4; ++r)
          J.Cb[(size_t)(gm0 + r) * J.Cstride + gn] = f2bf(acc[mi][ni][r] + bvs);
      } else {
        // mode 2: store so row-major [M][N] reads as a swizzled GEMM operand
#pragma unroll
        for (int r = 0; r < 4; ++r) {
          int row = gm0 + r;
          int col = (gn & ~63) | (((((gn >> 3) & 7) + row) & 7) << 3) | (gn & 7);
          J.Cb[(size_t)row * J.Cstride + col] = f2bf(acc[mi][ni][r] + bvs);
        }
      }
    }
  }
}

// ==== stage3: hybrid svgemm (blocks < nGemm) + scores/softmax (rest) ========
struct HJob {
  const unsigned short* A0;
  const unsigned short* Bt;
  unsigned short* Cb;
  int Astride, Bstride, Cstride, nTilesN, nt, tileBase;
};
struct S3Args {
  HJob g[2];
  int nGemm;                 // gemm blocks count (288)
  const unsigned short* qh;
  const unsigned short* s_key;
  const unsigned short* t_key;
  float* Wsw;
  float* Wtw;
};

__global__ __launch_bounds__(256) void stage3(S3Args A) {
  __shared__ __align__(16) unsigned char smem[16384];
  int tid = threadIdx.x;
  int wave = tid >> 6, lane = tid & 63;
  int lrow = lane & 15, lq = lane >> 4;

  if ((int)blockIdx.x < A.nGemm) {
    // ---- (2,2) 64x64 GEMM, pure-DMA double buffer, counted vmcnt ----
    int gt = blockIdx.x;
    HJob J = (gt >= A.g[1].tileBase) ? A.g[1] : A.g[0];
    int tl = gt - J.tileBase;
    int bm = (tl / J.nTilesN) * 64, bn = (tl % J.nTilesN) * 64;
    int wr = (wave >> 1) * 32, wc = (wave & 1) * 32;
    f32x4 acc[2][2] = {};
    int nt = J.nt;

    __shared__ __align__(16) unsigned short Lg[2][4096 + 4096];  // 32 KB
    auto stage2 = [&](int t, int buf) {
      const unsigned short* GA = J.A0 + (size_t)bm * J.Astride + (size_t)(t << 6);
      const unsigned short* GB = J.Bt + (size_t)bn * J.Bstride + (size_t)(t << 6);
#pragma unroll
      for (int p = 0; p < 2; ++p) {
        int s = p * 256 + tid;
        gload16(GA + (size_t)(s >> 3) * J.Astride + (s & 7) * 8,
                &Lg[buf][(size_t)(p * 256 + wave * 64) * 8]);
      }
#pragma unroll
      for (int p = 0; p < 2; ++p) {
        int s = p * 256 + tid;
        gload16(GB + (size_t)(s >> 3) * J.Bstride + (s & 7) * 8,
                &Lg[buf][4096 + (size_t)(p * 256 + wave * 64) * 8]);
      }
    };

    stage2(0, 0);
    if (nt > 1) stage2(1, 1);

    for (int t = 0; t < nt; ++t) {
      if (t + 1 < nt) asm volatile("s_waitcnt vmcnt(4)" ::: "memory");
      else            asm volatile("s_waitcnt vmcnt(0)" ::: "memory");
      SBAR();
      int cur = t & 1;
#pragma unroll
      for (int kc = 0; kc < 2; ++kc) {
        int kb = kc * 4 + lq;
        bf16x8 af[2], bv[2];
#pragma unroll
        for (int mi = 0; mi < 2; ++mi) {
          int r = wr + mi * 16 + lrow;
          af[mi] = *(const bf16x8*)&Lg[cur][r * 64 + ((kb + r) & 7) * 8];
        }
#pragma unroll
        for (int ni = 0; ni < 2; ++ni) {
          int r = wc + ni * 16 + lrow;
          bv[ni] = *(const bf16x8*)&Lg[cur][4096 + r * 64 + ((kb + r) & 7) * 8];
        }
#pragma unroll
        for (int mi = 0; mi < 2; ++mi)
#pragma unroll
          for (int ni = 0; ni < 2; ++ni)
            acc[mi][ni] = __builtin_amdgcn_mfma_f32_16x16x32_bf16(af[mi], bv[ni], acc[mi][ni], 0, 0, 0);
      }
      SBAR();
      if (t + 2 < nt) stage2(t + 2, cur);
    }
#pragma unroll
    for (int mi = 0; mi < 2; ++mi) {
#pragma unroll
      for (int ni = 0; ni < 2; ++ni) {
        int gn = bn + wc + ni * 16 + lrow;
        int gm0 = bm + wr + mi * 16 + lq * 4;
#pragma unroll
        for (int r = 0; r < 4; ++r)
          J.Cb[(size_t)(gm0 + r) * J.Cstride + gn] = f2bf(acc[mi][ni][r]);
      }
    }
  } else {
    // ---- scores + separable softmax -> Wsw/Wtw (f32 global) ----
    float (*red)[3][64][4] = (float(*)[3][64][4])smem;   // 12 KB
    int bid2 = blockIdx.x - A.nGemm;
    int b = bid2 >> 3, lc = bid2 & 7;
    int mat = wave >> 1, kh = wave & 1;
    int row0 = b * 128 + lc * 16;
    const unsigned short* qp = A.qh + (size_t)row0 * 512;
    const unsigned short* key = (mat ? A.s_key : A.t_key) + (size_t)b * 36 * 512;
    f32x4 acc[3] = {};
    for (int kc = kh * 8; kc < kh * 8 + 8; ++kc) {
      int k = kc * 32 + lq * 8;
      bf16x8 af = *(const bf16x8*)(qp + (size_t)lrow * 512 + k);
#pragma unroll
      for (int nf = 0; nf < 3; ++nf) {
        int n = nf * 16 + lrow; if (n > 35) n = 35;   // clamp; masked below
        bf16x8 bv = *(const bf16x8*)(key + (size_t)n * 512 + k);
        acc[nf] = __builtin_amdgcn_mfma_f32_16x16x32_bf16(af, bv, acc[nf], 0, 0, 0);
      }
    }
#pragma unroll
    for (int nf = 0; nf < 3; ++nf)
      *(f32x4*)&red[wave][nf][lane][0] = acc[nf];
    __syncthreads();

    if (kh == 0) {     // waves 0 (mat0 -> Wsw) and 2 (mat1 -> Wtw)
      const float ccs = 0.022097086912079608f;   // 0.5 / sqrt(512)
      float ex[3][4];
#pragma unroll
      for (int r = 0; r < 4; ++r) {
        float a0 = (red[wave][0][lane][r] + red[wave + 1][0][lane][r]) * ccs;
        float a1 = (red[wave][1][lane][r] + red[wave + 1][1][lane][r]) * ccs;
        float a2 = (lrow < 4)
            ? (red[wave][2][lane][r] + red[wave + 1][2][lane][r]) * ccs : -1e30f;
        float mx = fmaxf(fmaxf(a0, a1), a2);
        for (int s = 1; s < 16; s <<= 1) mx = fmaxf(mx, __shfl_xor(mx, s));
        float e0 = __expf(a0 - mx), e1 = __expf(a1 - mx);
        float e2 = (lrow < 4) ? __expf(a2 - mx) : 0.f;
        float sum = e0 + e1 + e2;
        for (int s = 1; s < 16; s <<= 1) sum += __shfl_xor(sum, s);
        float inv = 1.f / sum;
        ex[0][r] = e0 * inv; ex[1][r] = e1 * inv; ex[2][r] = e2 * inv;
      }
      float* W = mat ? A.Wtw : A.Wsw;
#pragma unroll
      for (int nf = 0; nf < 3; ++nf) {
        int col = nf * 16 + lrow;
        if (col < 36) {
#pragma unroll
          for (int r = 0; r < 4; ++r)
            W[(size_t)(row0 + lq * 4 + r) * 36 + col] = ex[nf][r];
        }
      }
    }
  }
}

// ==== wsum: out = relu(Pb + ws@svp + wt@tvp), 16 l-rows per block ==========
__global__ __launch_bounds__(256) void wsum(
    const float* __restrict__ Wsw, const float* __restrict__ Wtw,
    const unsigned short* __restrict__ svp, const unsigned short* __restrict__ tvp,
    const unsigned short* __restrict__ Pb, float* __restrict__ out) {
  __shared__ float wlT[2][36][16];   // 4.6 KB
  int b = blockIdx.x, lc = blockIdx.y;
  int tid = threadIdx.x;
  int row0 = b * 128 + lc * 16;
  for (int i = tid; i < 2 * 16 * 36; i += 256) {
    int m = i / 576, rem = i - m * 576;
    int l = rem / 36, j = rem - l * 36;
    wlT[m][j][l] = (m ? Wtw : Wsw)[(size_t)(row0 + l) * 36 + j];
  }
  __syncthreads();

  int lgrp = tid >> 6, hgrp = tid & 63;
  float a2[4][8] = {};
#pragma unroll
  for (int m = 0; m < 2; ++m) {
    const unsigned short* V = (m ? tvp : svp) + (size_t)b * 36 * 512;
    for (int j = 0; j < 36; ++j) {
      f32x4 wa = *(const f32x4*)&wlT[m][j][lgrp * 4];
      bf16x8 v = *(const bf16x8*)(V + (size_t)j * 512 + hgrp * 8);
      float vf[8];
#pragma unroll
      for (int hi = 0; hi < 8; ++hi) vf[hi] = bf2f((unsigned short)v[hi]);
#pragma unroll
      for (int li = 0; li < 4; ++li)
#pragma unroll
        for (int hi = 0; hi < 8; ++hi) a2[li][hi] += wa[li] * vf[hi];
    }
  }
#pragma unroll
  for (int li = 0; li < 4; ++li) {
    int R = row0 + lgrp * 4 + li;
    bf16x8 p = *(const bf16x8*)(Pb + (size_t)R * 512 + hgrp * 8);
    float* op = out + (size_t)R * 512 + hgrp * 8;
    f32x4 o0, o1;
#pragma unroll
    for (int hi = 0; hi < 4; ++hi) {
      o0[hi] = fmaxf(bf2f((unsigned short)p[hi]) + a2[li][hi], 0.f);
      o1[hi] = fmaxf(bf2f((unsigned short)p[4 + hi]) + a2[li][4 + hi], 0.f);
    }
    *(f32x4*)op = o0;
    *(f32x4*)(op + 4) = o1;
  }
}

// ---------------------------------------------------------------------------
extern "C" void kernel_launch(void* const* d_in, const int* in_sizes, int n_in,
                              void* d_out, int out_size, void* d_ws, size_t ws_size,
                              hipStream_t stream) {
  (void)in_sizes; (void)n_in; (void)out_size; (void)ws_size;
  const float* query = (const float*)d_in[0];
  const float* src   = (const float*)d_in[1];
  const float* trg   = (const float*)d_in[2];
  const float* Wq  = (const float*)d_in[3];  const float* bq  = (const float*)d_in[4];
  const float* Wsk = (const float*)d_in[5];  const float* bs  = (const float*)d_in[6];
  const float* Wtk = (const float*)d_in[7];  const float* bt  = (const float*)d_in[8];
  const float* Wsv = (const float*)d_in[9];  const float* bsv = (const float*)d_in[10];
  const float* Wtv = (const float*)d_in[11]; const float* btv = (const float*)d_in[12];
  const float* Wo  = (const float*)d_in[13]; const float* bo  = (const float*)d_in[14];

  // workspace (bf16 shorts unless noted) ~38 MB
  unsigned short* WqT    = (unsigned short*)d_ws;     // 512*512
  unsigned short* WsT    = WqT  + 512 * 512;          // 512*2048
  unsigned short* WtT    = WsT  + 512 * 2048;
  unsigned short* WsvT   = WtT  + 512 * 2048;
  unsigned short* WtvT   = WsvT + 512 * 2048;
  unsigned short* WoT    = WtvT + 512 * 2048;         // 512*1536
  unsigned short* queryB = WoT  + 512 * 1536;         // 4096*512 swz
  unsigned short* srcB   = queryB + 4096 * 512;       // 1152*2048 swz
  unsigned short* trgB   = srcB + 1152 * 2048;
  unsigned short* qh     = trgB + 1152 * 2048;        // 4096*512 plain
  unsigned short* s_key  = qh + 4096 * 512;           // 1152*512 plain
  unsigned short* t_key  = s_key + 1152 * 512;
  unsigned short* s_val  = t_key + 1152 * 512;        // 1152*512 A-swz (mode 2)
  unsigned short* t_val  = s_val + 1152 * 512;
  unsigned short* svp    = t_val + 1152 * 512;        // 1152*512 plain
  unsigned short* tvp    = svp + 1152 * 512;
  unsigned short* Pb     = tvp + 1152 * 512;          // 4096*512 plain
  float* Wsw = (float*)(Pb + 4096 * 512);             // 4096*36 f32
  float* Wtw = Wsw + 4096 * 36;
  float* out = (float*)d_out;

  // 1. prep: 6 weight transposes + 3 activation converts
  PrepJobs pj;
  const float* psrc[9] = { Wq, Wsk, Wtk, Wsv, Wtv, Wo, query, src, trg };
  unsigned short* pdst[9] = { WqT, WsT, WtT, WsvT, WtvT, WoT, queryB, srcB, trgB };
  int pK[9]    = { 512, 2048, 2048, 2048, 2048, 1536, 512, 2048, 2048 };
  int ptype[9] = { 0, 0, 0, 0, 0, 0, 1, 1, 1 };
  int prows[9] = { 0, 0, 0, 0, 0, 0, 4096, 1152, 1152 };
  int pbase = 0;
  for (int i = 0; i < 9; ++i) {
    pj.src[i] = psrc[i]; pj.dst[i] = pdst[i]; pj.K[i] = pK[i]; pj.type[i] = ptype[i];
    pj.base[i] = pbase;
    pbase += ptype[i] ? (prows[i] / 64) * (pK[i] / 64) : (pK[i] / 64) * 8;
  }
  prep<<<pbase, 256, 0, stream>>>(pj);

  // 2. merged projections (2,4)=64x128 tiles, 800 blocks:
  //    s_key, t_key (mode 0) | s_val, t_val (mode 2, A-format) | qh, Pb (mode 0)
  {
    GBatch pb;
    pb.swz = 0;
    int base = 0;
    const unsigned short* Aarr[4] = { srcB, trgB, srcB, trgB };
    const unsigned short* Barr[4] = { WsT, WtT, WsvT, WtvT };
    const float* biasArr[4] = { bs, bt, bsv, btv };
    unsigned short* Carr[4] = { s_key, t_key, s_val, t_val };
    for (int i = 0; i < 4; ++i) {     // 4 big K=2048 jobs: 18 m x 4 n = 72 tiles
      GJob& j = pb.j[i];
      j.A0 = Aarr[i]; j.Bt = Barr[i]; j.bias = biasArr[i]; j.Cb = Carr[i];
      j.Astride = 2048; j.Bstride = 2048; j.Cstride = 512;
      j.nTilesN = 4; j.nt = 32; j.mode = (i < 2) ? 0 : 2;
      j.tileBase = base; base += 18 * 4;
    }
    {                                  // qh = query@Wq + bq: 64x4 = 256 tiles
      GJob& j = pb.j[4];
      j.A0 = queryB; j.Bt = WqT; j.bias = bq; j.Cb = qh;
      j.Astride = 512; j.Bstride = 512; j.Cstride = 512;
      j.nTilesN = 4; j.nt = 8; j.mode = 0;
      j.tileBase = base; base += 64 * 4;
    }
    {                                  // Pb = query@Wo1 + bo: 256 tiles
      GJob& j = pb.j[5];
      j.A0 = queryB; j.Bt = WoT; j.bias = bo; j.Cb = Pb;
      j.Astride = 512; j.Bstride = 1536; j.Cstride = 512;
      j.nTilesN = 4; j.nt = 8; j.mode = 0;
      j.tileBase = base; base += 64 * 4;
    }
    pb.j[6] = pb.j[5]; pb.j[6].tileBase = 0x7fffffff;
    pb.njobs = 6;
    gemm_pipe<2, 4><<<base, 256, 0, stream>>>(pb);   // 800 blocks
  }

  // 3. stage3: svgemm (288 blocks) + scores/softmax (256 blocks) = 544 blocks
  {
    S3Args sa;
    HJob& a = sa.g[0];
    a.A0 = s_val; a.Bt = WoT + 512; a.Cb = svp;
    a.Astride = 512; a.Bstride = 1536; a.Cstride = 512;
    a.nTilesN = 8; a.nt = 8; a.tileBase = 0;
    HJob& b2 = sa.g[1];
    b2 = a;
    b2.A0 = t_val; b2.Bt = WoT + 1024; b2.Cb = tvp;
    b2.tileBase = 18 * 8;       // 144
    sa.nGemm = 288;
    sa.qh = qh; sa.s_key = s_key; sa.t_key = t_key;
    sa.Wsw = Wsw; sa.Wtw = Wtw;
    stage3<<<288 + 256, 256, 0, stream>>>(sa);
  }

  // 4. weighted sum + Pb + relu -> out (256 blocks)
  wsum<<<dim3(32, 8), 256, 0, stream>>>(Wsw, Wtw, svp, tvp, Pb, out);
}